// Round 17
// baseline (408.125 us; speedup 1.0000x reference)
//
#include <hip/hip_runtime.h>
#include <hip/hip_bf16.h>

#define DEV __device__ __forceinline__

static constexpr int LL   = 4096;   // 64x64
static constexpr int GG   = 4;      // 2 branches x 2 batch
static constexpr int CBC  = 262;    // 2*128 + 6

typedef float f32x4  __attribute__((ext_vector_type(4)));
typedef short bf16x8 __attribute__((ext_vector_type(8)));
typedef short bf16x4v __attribute__((ext_vector_type(4)));
typedef short bf16x2 __attribute__((ext_vector_type(2)));

DEV int map_l(int s, int k) {
    int m = (k & 2) ? (4095 - s) : s;
    if (k & 1) m = ((m & 63) << 6) | (m >> 6);
    return m;
}
DEV float silu_f(float x) { return x / (1.f + __expf(-x)); }
DEV short f2bf(float f) {
    union { __hip_bfloat16 h; short s; } u;
    u.h = __float2bfloat16(f);
    return u.s;
}
DEV float bf2f(short s) {
    return __uint_as_float(((unsigned)(unsigned short)s) << 16);
}
DEV bf16x8 pack8(float4 a, float4 b) {
    bf16x8 r;
    r[0]=f2bf(a.x); r[1]=f2bf(a.y); r[2]=f2bf(a.z); r[3]=f2bf(a.w);
    r[4]=f2bf(b.x); r[5]=f2bf(b.y); r[6]=f2bf(b.z); r[7]=f2bf(b.w);
    return r;
}
// 8-B-aligned bf16x8 load (two dwordx2) for reversed-direction bases
DEV bf16x8 load8u(const __hip_bfloat16* p) {
    bf16x4v lo = *(const bf16x4v*)p;
    bf16x4v hi = *(const bf16x4v*)(p + 4);
    bf16x8 r;
    r[0]=lo[0]; r[1]=lo[1]; r[2]=lo[2]; r[3]=lo[3];
    r[4]=hi[0]; r[5]=hi[1]; r[6]=hi[2]; r[7]=hi[3];
    return r;
}
DEV void store16(__hip_bfloat16* p, const float* v) {
    bf16x8 a, b;
    #pragma unroll
    for (int e = 0; e < 8; ++e) { a[e] = f2bf(v[e]); b[e] = f2bf(v[8+e]); }
    *(bf16x8*)p = a;
    *((bf16x8*)p + 1) = b;
}
DEV void storeT(float v, float* p) { *p = v; }
DEV void storeT(float v, __hip_bfloat16* p) { *p = __float2bfloat16(v); }

__global__ void sentinel_k(float* out) { out[0] = 1e30f; }

// ---------------- fused weight transposes -> bf16 Wt[n][k] blocks ----------------
// Wt_out has norm_w folded in: Wt_out[n][k] = W_out[k][n] * norm_w[k]
__global__ void wt_all_k(const float* __restrict__ W_skip, const float* __restrict__ W_xs,
                         const float* __restrict__ W_bcdt, const float* __restrict__ W_out,
                         const float* __restrict__ norm_w, __hip_bfloat16* __restrict__ Wt)
{
    int idx = blockIdx.x * 256 + threadIdx.x;
    if (idx < 73728) {
        int n = idx / 192, k = idx - n * 192;
        Wt[idx] = __float2bfloat16(W_skip[(size_t)k * 384 + n]);
    } else if (idx < 147456) {
        int r = idx - 73728;
        int n = r / 192, k = r - n * 192;
        Wt[idx] = __float2bfloat16(W_xs[(size_t)k * 384 + n]);
    } else if (idx < 208896) {
        int r = idx - 147456;
        int n = r / 192, k = r - n * 192;
        Wt[idx] = __float2bfloat16(n < 262 ? W_bcdt[(size_t)k * 262 + n] : 0.f);
    } else if (idx < 282624) {
        int r = idx - 208896;
        int n = r / 384, k = r - n * 384;
        Wt[idx] = __float2bfloat16(W_out[(size_t)k * 192 + n] * norm_w[k]);
    }
}

// ---------------- MFMA GEMM body: MODE 0 plain, 1 silu, 2 dual ----------------
template<int MODE, typename AT, typename OutT>
DEV void mgemm_body(const AT* __restrict__ A0, const AT* __restrict__ A1,
                    const __hip_bfloat16* __restrict__ Wt, OutT* __restrict__ C,
                    OutT* __restrict__ C2, int N, int Kd, int i0, int j0)
{
    int t = threadIdx.x;
    int w = t >> 6, lane = t & 63;
    int lr = lane & 15, kq = lane >> 4;
    const AT* arow[2];
    #pragma unroll
    for (int a = 0; a < 2; ++a) {
        int grow = i0 + w * 32 + a * 16 + lr;
        const AT* Ap = (grow < 8192) ? A0 : A1;
        arow[a] = Ap + (size_t)(grow & 8191) * Kd;
    }
    f32x4 acc[2][4] = {};
    for (int k0 = 0; k0 < Kd; k0 += 32) {
        int kb = k0 + kq * 8;
        bf16x8 af[2];
        #pragma unroll
        for (int a = 0; a < 2; ++a) {
            if constexpr (sizeof(AT) == 4)
                af[a] = pack8(*(const float4*)(arow[a] + kb), *(const float4*)(arow[a] + kb + 4));
            else
                af[a] = *(const bf16x8*)(arow[a] + kb);
        }
        #pragma unroll
        for (int b = 0; b < 4; ++b) {
            int n = j0 + b * 16 + lr;
            bf16x8 bfr = *(const bf16x8*)(Wt + (size_t)n * Kd + kb);
            #pragma unroll
            for (int a = 0; a < 2; ++a)
                acc[a][b] = __builtin_amdgcn_mfma_f32_16x16x32_bf16(af[a], bfr, acc[a][b], 0, 0, 0);
        }
    }
    #pragma unroll
    for (int a = 0; a < 2; ++a)
        #pragma unroll
        for (int b = 0; b < 4; ++b)
            #pragma unroll
            for (int r = 0; r < 4; ++r) {
                int row = i0 + w * 32 + a * 16 + kq * 4 + r;
                int col = j0 + b * 16 + lr;
                float v = acc[a][b][r];
                if constexpr (MODE == 0) {
                    if (col < N) storeT(v, &C[(size_t)row * N + col]);
                } else if constexpr (MODE == 1) {
                    if (col < N) storeT(silu_f(v), &C[(size_t)row * N + col]);
                } else {
                    if (col < 384) storeT(silu_f(v), &C[(size_t)row * 384 + col]);
                    else           storeT(v, &C2[(size_t)row * 384 + col - 384]);
                }
            }
}

// ---------------- MERGED input GEMMs: skip+xs dual (1536) | bcdt (640) ----------------
__global__ __launch_bounds__(256) void mgemm_in_k(
    const float* __restrict__ u1, const float* __restrict__ u2,
    const float* __restrict__ u21, const float* __restrict__ u12,
    const __hip_bfloat16* __restrict__ Wt_skip, const __hip_bfloat16* __restrict__ Wt_bcdt,
    __hip_bfloat16* __restrict__ z_silu, __hip_bfloat16* __restrict__ pre_xs,
    __hip_bfloat16* __restrict__ pre_bc)
{
    int bid = blockIdx.x;
    if (bid < 1536) {
        mgemm_body<2, float, __hip_bfloat16>(u1, u2, Wt_skip, z_silu, pre_xs,
                                             768, 192, (bid / 12) * 128, (bid % 12) * 64);
    } else {
        int b = bid - 1536;               // 640 blocks: (5, 128)
        mgemm_body<0, float, __hip_bfloat16>(u21, u12, Wt_bcdt, pre_bc, nullptr,
                                             CBC, 192, (b / 5) * 128, (b % 5) * 64);
    }
}

// ---------------- conv16<STRIDE>: halo-load + dwconv 16 channels into smem-ls ----------------
// smem layout: raw(h,w,c) = smem[(h*18+w)*17+c] (read phase); then ls(h,w,c) = smem[(h*17+w)*17+c]
template<int STRIDE>
DEV void conv16(const __hip_bfloat16* __restrict__ pre, const float* __restrict__ cw,
                const float* __restrict__ cbia, int g, int h0, int w0, int chb,
                float* smem, float (*wsm)[9], float* bsm, int t)
{
    if (t < 144) wsm[t / 9][t % 9] = cw[(chb + t / 9) * 9 + t % 9];
    if (t < 16)  bsm[t] = cbia[chb + t];
    for (int i = t; i < 18 * 18 * 8; i += 256) {
        int cp = i & 7;
        int hw = i >> 3;
        int ww2 = hw % 18, hh = hw / 18;
        int gh = h0 - 1 + hh, gw = w0 - 1 + ww2;
        float v0 = 0.f, v1 = 0.f;
        if ((unsigned)gh < 64u && (unsigned)gw < 64u) {
            bf16x2 pv = *(const bf16x2*)(pre + ((size_t)g * LL + gh * 64 + gw) * STRIDE + chb + cp * 2);
            v0 = bf2f(pv[0]); v1 = bf2f(pv[1]);
        }
        smem[(hh * 18 + ww2) * 17 + cp * 2]     = v0;
        smem[(hh * 18 + ww2) * 17 + cp * 2 + 1] = v1;
    }
    __syncthreads();
    int h = t >> 4, w2 = t & 15;
    float out[16];
    #pragma unroll
    for (int ch = 0; ch < 16; ++ch) {
        float acc = bsm[ch];
        #pragma unroll
        for (int dy = 0; dy < 3; ++dy)
            #pragma unroll
            for (int dx = 0; dx < 3; ++dx)
                acc += smem[((h + dy) * 18 + (w2 + dx)) * 17 + ch] * wsm[ch][dy * 3 + dx];
        out[ch] = silu_f(acc);
    }
    __syncthreads();
    #pragma unroll
    for (int ch = 0; ch < 16; ++ch)
        smem[(h * 17 + w2) * 17 + ch] = out[ch];
    __syncthreads();
}

// ---------------- FUSED prep: bt (2048) | cs/bs (2048) | dtscan (1536) | xtc (1536) ----------------
__global__ __launch_bounds__(256) void prep_k(
    const __hip_bfloat16* __restrict__ pre_bc, const float* __restrict__ cbw,
    const float* __restrict__ cbb, const __hip_bfloat16* __restrict__ pre_xs,
    const float* __restrict__ cxw, const float* __restrict__ cxb,
    const float* __restrict__ dt_bias, const float* __restrict__ A_logs,
    __hip_bfloat16* __restrict__ Bt, __hip_bfloat16* __restrict__ Cs,
    __hip_bfloat16* __restrict__ Bs, __hip_bfloat16* __restrict__ XtG,
    float* __restrict__ dt_arr, float* __restrict__ ac_arr,
    float* __restrict__ cdecay)
{
    __shared__ float smem[18 * 18 * 17];  // raw halo, later aliased as ls
    __shared__ float wsm[16][9];
    __shared__ float bsm[16];
    __shared__ float wsum[4];
    int bid = blockIdx.x;
    int t = threadIdx.x;
    if (bid < 2048) {
        // ---- Bt[g][n 512][s 4096], all 4 dirs; conv fused ----
        int nt = bid & 31;
        int rest = bid >> 5;
        int wt = rest & 3, ht2 = (rest >> 2) & 3, g = rest >> 4;
        int h0 = ht2 * 16, w0 = wt * 16;
        int kd = nt >> 3, ch0 = (nt & 7) * 16;       // B channels 0..127
        conv16<262>(pre_bc, cbw, cbb, g, h0, w0, ch0, smem, wsm, bsm, t);
        int pc = t >> 4, q = t & 15;
        int n = nt * 16 + pc;
        __hip_bfloat16* rowp = Bt + ((size_t)g * 512 + n) * 4096;
        float v[16];
        if (kd == 0) {
            #pragma unroll
            for (int e = 0; e < 16; ++e) v[e] = smem[(q * 17 + e) * 17 + pc];
            store16(rowp + (h0 + q) * 64 + w0, v);
        } else if (kd == 1) {
            #pragma unroll
            for (int e = 0; e < 16; ++e) v[e] = smem[(e * 17 + q) * 17 + pc];
            store16(rowp + (w0 + q) * 64 + h0, v);
        } else if (kd == 2) {
            #pragma unroll
            for (int e = 0; e < 16; ++e) v[e] = smem[(q * 17 + 15 - e) * 17 + pc];
            store16(rowp + 4095 - (h0 + q) * 64 - w0 - 15, v);
        } else {
            #pragma unroll
            for (int e = 0; e < 16; ++e) v[e] = smem[((15 - e) * 17 + q) * 17 + pc];
            store16(rowp + 4095 - (w0 + q) * 64 - h0 - 15, v);
        }
    } else if (bid < 4096) {
        // ---- Cs / Bs scan tensors [g][s][256] (kd0/kd1; kd2/3 read row 4095-s); conv fused ----
        int b2 = bid - 2048;
        int ct = b2 & 31;
        int rest = b2 >> 5;
        int wt = rest & 3, ht2 = (rest >> 2) & 3, g = rest >> 4;
        int h0 = ht2 * 16, w0 = wt * 16;
        bool isB = ct >= 16;
        int ctl = ct & 15;
        int kd = ctl >> 3, ch0 = (ctl & 7) * 16;
        int chb = (isB ? 0 : 128) + ch0;
        conv16<262>(pre_bc, cbw, cbb, g, h0, w0, chb, smem, wsm, bsm, t);
        __hip_bfloat16* dst = isB ? Bs : Cs;
        int h = t >> 4, w2 = t & 15;
        int s = (kd == 0) ? (h0 + h) * 64 + (w0 + w2) : (w0 + w2) * 64 + (h0 + h);
        float v[16];
        #pragma unroll
        for (int e = 0; e < 16; ++e) v[e] = smem[(h * 17 + w2) * 17 + e];
        store16(dst + ((size_t)g * 4096 + s) * 256 + kd * 128 + ch0, v);
    } else if (bid < 5632) {
        // ---- dt: 9-tap conv inline + softplus + per-chunk cumsum (shuffle scan) ----
        int b3 = bid - 4096;              // ht + 24*(c + 16*g), 1536
        int ht = b3 % 24;
        int gc = b3 / 24;
        int c = gc & 15, g = gc >> 4;
        int k = ht / 6, h = ht % 6;
        int s = c * 256 + t;
        int l = map_l(s, k);
        int ch = 256 + h;
        float acc = cbb[ch];
        int hh0 = l >> 6, ww0 = l & 63;
        #pragma unroll
        for (int dy = 0; dy < 3; ++dy) {
            int gh = hh0 + dy - 1;
            if ((unsigned)gh >= 64u) continue;
            #pragma unroll
            for (int dx = 0; dx < 3; ++dx) {
                int gw = ww0 + dx - 1;
                if ((unsigned)gw >= 64u) continue;
                acc += __bfloat162float(pre_bc[((size_t)g * LL + gh * 64 + gw) * 262 + ch]) *
                       cbw[ch * 9 + dy * 3 + dx];
            }
        }
        float raw = silu_f(acc) + dt_bias[ht];
        float dtv = raw > 20.f ? raw : log1pf(__expf(raw));
        float dA = dtv * (-__expf(A_logs[ht]));
        float v = dA;
        #pragma unroll
        for (int off = 1; off < 64; off <<= 1) {
            float u = __shfl_up(v, off);
            if ((t & 63) >= off) v += u;
        }
        if ((t & 63) == 63) wsum[t >> 6] = v;
        __syncthreads();
        float add = 0.f;
        #pragma unroll
        for (int w2 = 0; w2 < 3; ++w2)
            if (w2 < (t >> 6)) add += wsum[w2];
        float cum = v + add;
        size_t base = ((size_t)g * 24 + ht) * LL + s;
        dt_arr[base] = dtv;
        ac_arr[base] = cum;
        if (t == 255) cdecay[(g * 24 + ht) * 16 + c] = __expf(cum);
    } else {
        // ---- xtc: dwconv(x) + transpose-store to XtG (2 scan dirs); conv fused ----
        int b4 = bid - 5632;              // 24 pct x 4 wt x 4 ht x 4 g = 1536
        int pct = b4 % 24;
        int rest = b4 / 24;
        int wt = rest & 3, ht2 = (rest >> 2) & 3, g = rest >> 4;
        int h0 = ht2 * 16, w0 = wt * 16, pc0 = pct * 16;
        conv16<384>(pre_xs, cxw, cxb, g, h0, w0, pc0, smem, wsm, bsm, t);
        int pc = t >> 4, q = t & 15;
        float v[16];
        size_t rowbase;
        #pragma unroll
        for (int e = 0; e < 16; ++e) v[e] = smem[(q * 17 + e) * 17 + pc];
        rowbase = ((size_t)(g * 2 + 0) * 384 + pc0 + pc) * 4096;
        store16(XtG + rowbase + (h0 + q) * 64 + w0, v);
        #pragma unroll
        for (int e = 0; e < 16; ++e) v[e] = smem[(e * 17 + q) * 17 + pc];
        rowbase = ((size_t)(g * 2 + 1) * 384 + pc0 + pc) * 4096;
        store16(XtG + rowbase + (w0 + q) * 64 + h0, v);
    }
}

// ---------------- MERGED cb (256) + states (3072): both depend only on prep ----------------
__global__ __launch_bounds__(256) void cbst_k(
    const __hip_bfloat16* __restrict__ Cs, const __hip_bfloat16* __restrict__ Bs,
    __hip_bfloat16* __restrict__ CBm,
    const __hip_bfloat16* __restrict__ XtG, const __hip_bfloat16* __restrict__ Bt,
    const float* __restrict__ dt_arr, const float* __restrict__ ac_arr,
    __hip_bfloat16* __restrict__ states)
{
    __shared__ float wsh[256];
    __shared__ short xw[64][264];         // weighted x, +8 pad -> 2-way bank alias (free)
    int bid = blockIdx.x;
    int t = threadIdx.x;
    int w = t >> 6, lane = t & 63;
    int lr = lane & 15, kq = lane >> 4;
    if (bid < 256) {
        // ---- CB[gc][i][j] = sum_n C[i,n]*B[j,n] ----
        int jq = bid & 3;
        int gc = bid >> 2;
        int c = gc & 15, g = gc >> 4;
        const __hip_bfloat16* cg = Cs + (size_t)g * 4096 * 256;
        const __hip_bfloat16* bsg = Bs + (size_t)g * 4096 * 256;
        f32x4 acc[4][4] = {};
        for (int ks = 0; ks < 16; ++ks) {
            int n0 = ks * 32 + kq * 8;
            int kd = n0 >> 7, nn = n0 & 127;
            int col = ((kd & 1) << 7) + nn;
            bf16x8 bfr[4];
            #pragma unroll
            for (int jt = 0; jt < 4; ++jt) {
                int j = jq * 64 + jt * 16 + lr;
                int s = c * 256 + j;
                int row = (kd < 2) ? s : 4095 - s;
                bfr[jt] = *(const bf16x8*)(bsg + (size_t)row * 256 + col);
            }
            #pragma unroll
            for (int iq = 0; iq < 4; ++iq) {
                int i = (w * 4 + iq) * 16 + lr;
                int s = c * 256 + i;
                int row = (kd < 2) ? s : 4095 - s;
                bf16x8 af = *(const bf16x8*)(cg + (size_t)row * 256 + col);
                #pragma unroll
                for (int jt = 0; jt < 4; ++jt)
                    acc[iq][jt] = __builtin_amdgcn_mfma_f32_16x16x32_bf16(af, bfr[jt], acc[iq][jt], 0, 0, 0);
            }
        }
        __hip_bfloat16* ob = CBm + (size_t)gc * 65536;
        #pragma unroll
        for (int iq = 0; iq < 4; ++iq)
            #pragma unroll
            for (int jt = 0; jt < 4; ++jt)
                #pragma unroll
                for (int r = 0; r < 4; ++r) {
                    int i = (w * 4 + iq) * 16 + kq * 4 + r;
                    int j = jq * 64 + jt * 16 + lr;
                    ob[(size_t)i * 256 + j] = __float2bfloat16(acc[iq][jt][r]);
                }
        return;
    }
    // ---- states, n-split: S[p, n-half] = sum_j w_j x[j,p] B[j,n] ----
    int sb = bid - 256;
    int task = (sb & 7) * 384 + (sb >> 3);  // XCD swizzle (perf only)
    int ht = task % 24;
    int rest = task / 24;                 // nh + 2*gc
    int nh = rest & 1;
    int gc = rest >> 1;
    int c = gc & 15, g = gc >> 4;
    int kd = ht / 6;
    bool rev = kd >= 2;
    int c0 = (ht % 6) * 64;
    int n0 = nh * 256;
    const float* dtp = dt_arr + ((size_t)g * 24 + ht) * LL + c * 256;
    const float* acp = ac_arr + ((size_t)g * 24 + ht) * LL + c * 256;
    float ac_last = acp[255];
    wsh[t] = __expf(ac_last - acp[t]) * dtp[t];
    __syncthreads();
    const __hip_bfloat16* xg = XtG + ((size_t)(g * 2 + (kd & 1)) * 384 + c0) * 4096;
    #pragma unroll
    for (int r8 = 0; r8 < 8; ++r8) {
        int id = t + 256 * r8;            // 0..2047
        int p = id >> 5;
        int jc = (id & 31) * 8;
        bf16x8 xv;
        if (!rev) {
            xv = *(const bf16x8*)(xg + (size_t)p * 4096 + c * 256 + jc);
        } else {
            bf16x8 tmp = load8u(xg + (size_t)p * 4096 + 4088 - c * 256 - jc);
            #pragma unroll
            for (int e = 0; e < 8; ++e) xv[e] = tmp[7 - e];
        }
        bf16x8 o;
        #pragma unroll
        for (int e = 0; e < 8; ++e) o[e] = f2bf(bf2f(xv[e]) * wsh[jc + e]);
        *(bf16x8*)&xw[p][jc] = o;
    }
    __syncthreads();
    const __hip_bfloat16* btg = Bt + ((size_t)g * 512 + n0) * 4096;
    f32x4 acc[4][4] = {};                 // [pt][nt], 64p x 256n (this half)
    for (int ks = 0; ks < 8; ++ks) {
        int j0 = ks * 32 + kq * 8;
        bf16x8 af[4];
        #pragma unroll
        for (int pt = 0; pt < 4; ++pt)
            af[pt] = *(const bf16x8*)&xw[pt * 16 + lr][j0];
        #pragma unroll
        for (int nt = 0; nt < 4; ++nt) {
            int nl = (w * 4 + nt) * 16 + lr;
            bf16x8 bv = *(const bf16x8*)(btg + (size_t)nl * 4096 + c * 256 + j0);
            #pragma unroll
            for (int pt = 0; pt < 4; ++pt)
                acc[pt][nt] = __builtin_amdgcn_mfma_f32_16x16x32_bf16(af[pt], bv, acc[pt][nt], 0, 0, 0);
        }
    }
    __hip_bfloat16* ob = states + ((size_t)gc * 24 + ht) * 32768 + n0;
    #pragma unroll
    for (int pt = 0; pt < 4; ++pt)
        #pragma unroll
        for (int nt = 0; nt < 4; ++nt)
            #pragma unroll
            for (int r = 0; r < 4; ++r) {
                int p = pt * 16 + kq * 4 + r;
                int nl = (w * 4 + nt) * 16 + lr;
                ob[(size_t)p * 512 + nl] = __float2bfloat16(acc[pt][nt][r]);
            }
}

// ---------------- inter-chunk scan, in place (vectorized bf16x8) ----------------
__global__ void scan_k(__hip_bfloat16* __restrict__ states, const float* __restrict__ cdecay)
{
    int idx = blockIdx.x * 256 + threadIdx.x;   // GG*24*64*512/8 = 393,216
    int g = idx / 98304;
    int r = idx - g * 98304;
    int ht = r >> 12;
    int pn8 = (r & 4095) * 8;
    const float* cd = cdecay + (g * 24 + ht) * 16;
    __hip_bfloat16* base = states + ((size_t)g * 384 + ht) * 32768 + pn8;
    float S[8] = {};
    #pragma unroll
    for (int c2 = 0; c2 < 16; ++c2) {
        bf16x8* p = (bf16x8*)(base + (size_t)c2 * 786432);
        bf16x8 tmp = *p;
        bf16x8 o;
        float dec = cd[c2];
        #pragma unroll
        for (int e = 0; e < 8; ++e) {
            o[e] = f2bf(S[e]);
            S[e] = S[e] * dec + bf2f(tmp[e]);
        }
        *p = o;
    }
}

// ---------------- MFMA y (round-13 proven shape): x LDS-staged upfront ----------------
__global__ __launch_bounds__(256) void yk(
    const __hip_bfloat16* __restrict__ XtG, const __hip_bfloat16* __restrict__ Cs,
    const __hip_bfloat16* __restrict__ CBm, const __hip_bfloat16* __restrict__ prev,
    const float* __restrict__ dt_arr, const float* __restrict__ ac_arr,
    const float* __restrict__ Ds, __hip_bfloat16* __restrict__ y4)
{
    __shared__ float acs[256], dts[256], ejdt[256];
    __shared__ short xl[64][264];         // x tile (scan order, rev folded), +8 pad
    int task = (blockIdx.x & 7) * 192 + (blockIdx.x >> 3);  // XCD swizzle (perf only)
    int ht = task % 24;
    int gc = task / 24;
    int c = gc & 15, g = gc >> 4;
    int kd = ht / 6;
    bool rev = kd >= 2;
    int c0 = (ht % 6) * 64;
    int t = threadIdx.x;
    int w = t >> 6, lane = t & 63;
    int lr = lane & 15, kq = lane >> 4;
    size_t abase = ((size_t)g * 24 + ht) * LL + c * 256;
    float ac_own = ac_arr[abase + t];
    float dt_own = dt_arr[abase + t];
    acs[t] = ac_own;
    dts[t] = dt_own;
    float acb0 = __shfl(ac_own, (t & 63) & ~31);
    ejdt[t] = __expf(acb0 - ac_own) * dt_own;
    const __hip_bfloat16* xg = XtG + ((size_t)(g * 2 + (kd & 1)) * 384 + c0) * 4096;
    #pragma unroll
    for (int r8 = 0; r8 < 8; ++r8) {
        int id = t + 256 * r8;
        int p = id >> 5;
        int jc = (id & 31) * 8;
        bf16x8 xv;
        if (!rev) {
            xv = *(const bf16x8*)(xg + (size_t)p * 4096 + c * 256 + jc);
        } else {
            bf16x8 tmp = load8u(xg + (size_t)p * 4096 + 4088 - c * 256 - jc);
            #pragma unroll
            for (int e = 0; e < 8; ++e) xv[e] = tmp[7 - e];
        }
        *(bf16x8*)&xl[p][jc] = xv;
    }
    __syncthreads();
    const __hip_bfloat16* cbb = CBm + (size_t)gc * 65536;
    const __hip_bfloat16* cg = Cs + (size_t)g * 4096 * 256;
    f32x4 acc[4][4] = {};
    // ---- term2 FIRST (unscaled): C @ prev^T, ping-pong double-buffered loads ----
    const __hip_bfloat16* pv = prev + ((size_t)gc * 24 + ht) * 32768;
    auto ld2 = [&](int ns, bf16x8* afq, bf16x8* pb) {
        int n0 = ns * 32 + kq * 8;
        int kd2 = n0 >> 7, nn = n0 & 127;
        int col = ((kd2 & 1) << 7) + nn;
        #pragma unroll
        for (int q = 0; q < 4; ++q) {
            int i = (w + 4 * q) * 16 + lr;
            int s = c * 256 + i;
            int row = (kd2 < 2) ? s : 4095 - s;
            afq[q] = *(const bf16x8*)(cg + (size_t)row * 256 + col);
        }
        #pragma unroll
        for (int pt = 0; pt < 4; ++pt)
            pb[pt] = *(const bf16x8*)(pv + (size_t)(pt * 16 + lr) * 512 + n0);
    };
    auto fma2 = [&](bf16x8* afq, bf16x8* pb) {
        #pragma unroll
        for (int q = 0; q < 4; ++q)
            #pragma unroll
            for (int pt = 0; pt < 4; ++pt)
                acc[q][pt] = __builtin_amdgcn_mfma_f32_16x16x32_bf16(afq[q], pb[pt], acc[q][pt], 0, 0, 0);
    };
    {
        bf16x8 afA[4], pbA[4], afB[4], pbB[4];
        ld2(0, afA, pbA);
        #pragma unroll
        for (int ns = 0; ns < 16; ns += 2) {
            if (ns + 1 < 16) ld2(ns + 1, afB, pbB);
            fma2(afA, pbA);
            if (ns + 2 < 16) ld2(ns + 2, afA, pbA);
            fma2(afB, pbB);
        }
    }
    // ---- scale term2 by exp(ac_i) in place ----
    #pragma unroll
    for (int q = 0; q < 4; ++q)
        #pragma unroll
        for (int r = 0; r < 4; ++r) {
            float er = __expf(acs[(w + 4 * q) * 16 + kq * 4 + r]);
            #pragma unroll
            for (int pt = 0; pt < 4; ++pt) acc[q][pt][r] *= er;
        }
    // ---- term1: causal M @ x; M = CB * exp(ac_i-ac_b) * ejdt; x from LDS ----
    float aci_q[4];
    #pragma unroll
    for (int q = 0; q < 4; ++q) aci_q[q] = acs[(w + 4 * q) * 16 + lr];
    for (int ks = 0; ks < 8; ++ks) {
        int j0 = ks * 32 + kq * 8;
        bf16x8 xb[4];
        #pragma unroll
        for (int pt = 0; pt < 4; ++pt)
            xb[pt] = *(const bf16x8*)&xl[pt * 16 + lr][j0];
        float acb = acs[ks * 32];
        float ej[8];
        #pragma unroll
        for (int e = 0; e < 8; ++e) ej[e] = ejdt[j0 + e];
        #pragma unroll
        for (int q = 0; q < 4; ++q) {
            int rt = w + 4 * q;
            if (rt < 2 * ks) continue;               // whole j-block above diagonal
            int i = rt * 16 + lr;
            float r2 = __expf(aci_q[q] - acb);
            bf16x8 cb8 = *(const bf16x8*)(cbb + (size_t)i * 256 + j0);
            bf16x8 af;
            if (rt >= 2 * ks + 2) {                  // full tile: no mask needed
                #pragma unroll
                for (int e = 0; e < 8; ++e)
                    af[e] = f2bf(r2 * ej[e] * bf2f(cb8[e]));
            } else {                                 // diagonal tile
                #pragma unroll
                for (int e = 0; e < 8; ++e) {
                    float coef = r2 * ej[e] * bf2f(cb8[e]);
                    af[e] = (j0 + e <= i) ? f2bf(coef) : (short)0;
                }
            }
            #pragma unroll
            for (int pt = 0; pt < 4; ++pt)
                acc[q][pt] = __builtin_amdgcn_mfma_f32_16x16x32_bf16(af, xb[pt], acc[q][pt], 0, 0, 0);
        }
    }
    // ---- epilogue: + Ds*x (from LDS), coalesced bf16 store to y4 (scan order) ----
    float Dsv = Ds[ht];
    __hip_bfloat16* yb = y4 + (((size_t)(g * 4 + kd) * 4096 + c * 256) * 384) + c0;
    #pragma unroll
    for (int q = 0; q < 4; ++q) {
        int rt = w + 4 * q;
        #pragma unroll
        for (int pt = 0; pt < 4; ++pt) {
            int p = pt * 16 + lr;
            int ibase = rt * 16 + kq * 4;
            bf16x4v x4 = *(const bf16x4v*)&xl[p][ibase];
            #pragma unroll
            for (int r = 0; r < 4; ++r) {
                int i = ibase + r;
                float xv = bf2f(x4[r]);
                yb[(size_t)i * 384 + p] = __float2bfloat16(acc[q][pt][r] + Dsv * xv);
            }
        }
    }
}

// ---------------- FUSED gate + output GEMM: 256 blocks x 64 rows ----------------
// phase1: gate 64 rows (4 lanes/row, 96 cols each, f32 in regs -> bit-identical rounding),
//         bf16 gn tile to LDS. phase2: 64x192 MFMA GEMM (K=384) from LDS A, Wt_out B.
__global__ __launch_bounds__(256) void gateout_k(
    const __hip_bfloat16* __restrict__ y4, const __hip_bfloat16* __restrict__ z_silu,
    const __hip_bfloat16* __restrict__ Wt_out, float* __restrict__ out)
{
    __shared__ short gnl[64][392];        // stride 784B: 196 dw, %32=4 -> 2 lanes/bank (free)
    int b = blockIdx.x;
    int t = threadIdx.x;
    int row0 = b * 64;
    // ---- phase 1: gate ----
    {
        int rloc = t >> 2, part = t & 3;
        int row = row0 + rloc;
        int g = row >> 12, l = row & 4095;
        int Tl = ((l & 63) << 6) | (l >> 6);
        const __hip_bfloat16* p0 = y4 + ((size_t)(g * 4 + 0) * 4096 + l) * 384;
        const __hip_bfloat16* p1 = y4 + ((size_t)(g * 4 + 1) * 4096 + Tl) * 384;
        const __hip_bfloat16* p2 = y4 + ((size_t)(g * 4 + 2) * 4096 + 4095 - l) * 384;
        const __hip_bfloat16* p3 = y4 + ((size_t)(g * 4 + 3) * 4096 + 4095 - Tl) * 384;
        const __hip_bfloat16* zp = z_silu + ((size_t)g * LL + l) * 384;
        int cb = part * 96;
        float vf[96];
        float ssq = 0.f;
        #pragma unroll
        for (int cg = 0; cg < 12; ++cg) {
            int cc = cb + cg * 8;
            bf16x8 a0 = *(const bf16x8*)(p0 + cc);
            bf16x8 a1 = *(const bf16x8*)(p1 + cc);
            bf16x8 a2 = *(const bf16x8*)(p2 + cc);
            bf16x8 a3 = *(const bf16x8*)(p3 + cc);
            bf16x8 zv = *(const bf16x8*)(zp + cc);
            #pragma unroll
            for (int e = 0; e < 8; ++e) {
                float yf = bf2f(a0[e]) + bf2f(a1[e]) + bf2f(a2[e]) + bf2f(a3[e]);
                float v = yf * bf2f(zv[e]);
                vf[cg * 8 + e] = v;
                ssq += v * v;
            }
        }
        ssq += __shfl_xor(ssq, 1);
        ssq += __shfl_xor(ssq, 2);
        float rs = rsqrtf(ssq * (1.f / 384.f) + 1e-5f);
        #pragma unroll
        for (int cg = 0; cg < 12; ++cg) {
            bf16x8 o;
            #pragma unroll
            for (int e = 0; e < 8; ++e) o[e] = f2bf(vf[cg * 8 + e] * rs);
            *(bf16x8*)&gnl[rloc][cb + cg * 8] = o;
        }
    }
    __syncthreads();
    // ---- phase 2: 64x192 GEMM, K=384 ----
    int w = t >> 6, lane = t & 63;
    int lr = lane & 15, kq = lane >> 4;
    f32x4 acc[4][3] = {};
    for (int k0 = 0; k0 < 384; k0 += 32) {
        int kb = k0 + kq * 8;
        bf16x8 af[4];
        #pragma unroll
        for (int a = 0; a < 4; ++a)
            af[a] = *(const bf16x8*)&gnl[a * 16 + lr][kb];
        #pragma unroll
        for (int b2 = 0; b2 < 3; ++b2) {
            int n = w * 48 + b2 * 16 + lr;
            bf16x8 bfr = *(const bf16x8*)(Wt_out + (size_t)n * 384 + kb);
            #pragma unroll
            for (int a = 0; a < 4; ++a)
                acc[a][b2] = __builtin_amdgcn_mfma_f32_16x16x32_bf16(af[a], bfr, acc[a][b2], 0, 0, 0);
        }
    }
    #pragma unroll
    for (int a = 0; a < 4; ++a)
        #pragma unroll
        for (int b2 = 0; b2 < 3; ++b2)
            #pragma unroll
            for (int r = 0; r < 4; ++r) {
                int row = row0 + a * 16 + kq * 4 + r;
                int col = w * 48 + b2 * 16 + lr;
                out[(size_t)row * 192 + col] = acc[a][b2][r];
            }
}

extern "C" void kernel_launch(void* const* d_in, const int* in_sizes, int n_in,
                              void* d_out, int out_size, void* d_ws, size_t ws_size,
                              hipStream_t stream)
{
    const float* u1      = (const float*)d_in[0];
    const float* u2      = (const float*)d_in[1];
    const float* u21     = (const float*)d_in[2];
    const float* u12     = (const float*)d_in[3];
    const float* W_skip  = (const float*)d_in[4];
    const float* W_xs    = (const float*)d_in[5];
    const float* W_bcdt  = (const float*)d_in[6];
    const float* cxw     = (const float*)d_in[7];
    const float* cxb     = (const float*)d_in[8];
    const float* cbw     = (const float*)d_in[9];
    const float* cbb     = (const float*)d_in[10];
    const float* dt_bias = (const float*)d_in[11];
    const float* A_logs  = (const float*)d_in[12];
    const float* Ds      = (const float*)d_in[13];
    const float* norm_w  = (const float*)d_in[14];
    const float* W_out   = (const float*)d_in[15];
    float* out = (float*)d_out;

    char* w = (char*)d_ws;
    size_t o_y4  = 0;                         // 50,331,648 bf16 y4
    size_t o_st  = o_y4 + 50331648;           // 100,663,296 bf16 states/prev (early: pre_bc@0, pre_xs@8.65M)
    size_t o_z   = o_st + 100663296;          // 12,582,912 bf16 z_silu
    size_t o_xtg = o_z  + 12582912;           // 25,165,824 bf16 XtG (2 dirs)
    size_t o_bt  = o_xtg + 25165824;          // 16,777,216 bf16 Bt
    size_t o_cs  = o_bt + 16777216;           //  8,388,608 bf16 C_scan
    size_t o_cbm = o_cs + 8388608;            //  8,388,608 bf16 CBm
    size_t o_dt  = o_cbm + 8388608;           //  1,572,864 f32 dt_arr
    size_t o_ac  = o_dt + 1572864;            //  1,572,864 f32 ac_arr
    size_t o_cd  = o_ac + 1572864;            //      8,192 f32 cdecay
    size_t o_wt  = o_cd + 8192;               //    589,824 bf16 Wt (skip|xs|bcdt|out)
    size_t o_bs  = o_wt + 589824;             //  8,388,608 bf16 B_scan
    size_t total = o_bs + 8388608;            // = 234,430,464 B (< proven 238.5 MB)
    if (total > ws_size) {
        sentinel_k<<<1, 1, 0, stream>>>(out); // absmax ~1e30 => workspace too small
        return;
    }
    __hip_bfloat16* y4     = (__hip_bfloat16*)(w + o_y4);
    __hip_bfloat16* states = (__hip_bfloat16*)(w + o_st);
    __hip_bfloat16* z_silu = (__hip_bfloat16*)(w + o_z);
    __hip_bfloat16* XtG    = (__hip_bfloat16*)(w + o_xtg);
    __hip_bfloat16* Bt     = (__hip_bfloat16*)(w + o_bt);
    __hip_bfloat16* Cs     = (__hip_bfloat16*)(w + o_cs);
    __hip_bfloat16* CBm    = (__hip_bfloat16*)(w + o_cbm);
    float*          dt_arr = (float*)(w + o_dt);
    float*          ac_arr = (float*)(w + o_ac);
    float*          cdecay = (float*)(w + o_cd);
    __hip_bfloat16* Wt     = (__hip_bfloat16*)(w + o_wt);
    __hip_bfloat16* Bs     = (__hip_bfloat16*)(w + o_bs);
    __hip_bfloat16* Wt_skip = Wt;                       // skip|xs contiguous (N=768)
    __hip_bfloat16* Wt_bcdt = Wt + 147456;
    __hip_bfloat16* Wt_out  = Wt + 208896;
    // transient aliases
    __hip_bfloat16* pre_bc = (__hip_bfloat16*)(w + o_st);           // dead after prep_k
    __hip_bfloat16* pre_xs = (__hip_bfloat16*)(w + o_st + 8650752); // dead after prep_k

    dim3 blk(256);
    // 0. fused weight transposes (norm_w folded into Wt_out)
    wt_all_k<<<dim3(1104), blk, 0, stream>>>(W_skip, W_xs, W_bcdt, W_out, norm_w, Wt);
    // 1. merged input GEMMs (MFMA): skip+xs dual-out | bcdt
    mgemm_in_k<<<dim3(2176), blk, 0, stream>>>(u1, u2, u21, u12, Wt_skip, Wt_bcdt,
                                               z_silu, pre_xs, pre_bc);
    // 2. fused prep: Bt | Cs/Bs | dtscan | xtc (one dispatch, conv inline)
    prep_k<<<dim3(7168), blk, 0, stream>>>(pre_bc, cbw, cbb, pre_xs, cxw, cxb,
                                           dt_bias, A_logs, Bt, Cs, Bs, XtG,
                                           dt_arr, ac_arr, cdecay);
    // 3. merged CB (MFMA) + per-chunk states (MFMA, XCD-swizzled, n-split)
    cbst_k<<<dim3(3328), blk, 0, stream>>>(Cs, Bs, CBm, XtG, Bt, dt_arr, ac_arr, states);
    // 4. inter-chunk scan (in place -> prev states, bf16x8-vectorized)
    scan_k<<<dim3(1536), blk, 0, stream>>>(states, cdecay);
    // 5. y (MFMA, XCD-swizzled, x LDS-staged, full-p) -> per-direction y4
    yk<<<dim3(1536), blk, 0, stream>>>(XtG, Cs, CBm, states, dt_arr, ac_arr, Ds, y4);
    // 6. fused gate + RMSNorm + output GEMM (norm_w folded in Wt_out)
    gateout_k<<<dim3(256), blk, 0, stream>>>(y4, z_silu, Wt_out, out);
}

// Round 18
// 401.585 us; speedup vs baseline: 1.0163x; 1.0163x over previous
//
#include <hip/hip_runtime.h>
#include <hip/hip_bf16.h>

#define DEV __device__ __forceinline__

static constexpr int LL   = 4096;   // 64x64
static constexpr int GG   = 4;      // 2 branches x 2 batch
static constexpr int CBC  = 262;    // 2*128 + 6

typedef float f32x4  __attribute__((ext_vector_type(4)));
typedef short bf16x8 __attribute__((ext_vector_type(8)));
typedef short bf16x4v __attribute__((ext_vector_type(4)));
typedef short bf16x2 __attribute__((ext_vector_type(2)));

DEV int map_l(int s, int k) {
    int m = (k & 2) ? (4095 - s) : s;
    if (k & 1) m = ((m & 63) << 6) | (m >> 6);
    return m;
}
DEV float silu_f(float x) { return x / (1.f + __expf(-x)); }
DEV short f2bf(float f) {
    union { __hip_bfloat16 h; short s; } u;
    u.h = __float2bfloat16(f);
    return u.s;
}
DEV float bf2f(short s) {
    return __uint_as_float(((unsigned)(unsigned short)s) << 16);
}
DEV bf16x8 pack8(float4 a, float4 b) {
    bf16x8 r;
    r[0]=f2bf(a.x); r[1]=f2bf(a.y); r[2]=f2bf(a.z); r[3]=f2bf(a.w);
    r[4]=f2bf(b.x); r[5]=f2bf(b.y); r[6]=f2bf(b.z); r[7]=f2bf(b.w);
    return r;
}
// 8-B-aligned bf16x8 load (two dwordx2) for reversed-direction bases
DEV bf16x8 load8u(const __hip_bfloat16* p) {
    bf16x4v lo = *(const bf16x4v*)p;
    bf16x4v hi = *(const bf16x4v*)(p + 4);
    bf16x8 r;
    r[0]=lo[0]; r[1]=lo[1]; r[2]=lo[2]; r[3]=lo[3];
    r[4]=hi[0]; r[5]=hi[1]; r[6]=hi[2]; r[7]=hi[3];
    return r;
}
DEV void store16(__hip_bfloat16* p, const float* v) {
    bf16x8 a, b;
    #pragma unroll
    for (int e = 0; e < 8; ++e) { a[e] = f2bf(v[e]); b[e] = f2bf(v[8+e]); }
    *(bf16x8*)p = a;
    *((bf16x8*)p + 1) = b;
}
DEV void storeT(float v, float* p) { *p = v; }
DEV void storeT(float v, __hip_bfloat16* p) { *p = __float2bfloat16(v); }

__global__ void sentinel_k(float* out) { out[0] = 1e30f; }

// ---------------- fused weight transposes -> bf16 Wt[n][k] blocks ----------------
// Wt_out has norm_w folded in: Wt_out[n][k] = W_out[k][n] * norm_w[k]
__global__ void wt_all_k(const float* __restrict__ W_skip, const float* __restrict__ W_xs,
                         const float* __restrict__ W_bcdt, const float* __restrict__ W_out,
                         const float* __restrict__ norm_w, __hip_bfloat16* __restrict__ Wt)
{
    int idx = blockIdx.x * 256 + threadIdx.x;
    if (idx < 73728) {
        int n = idx / 192, k = idx - n * 192;
        Wt[idx] = __float2bfloat16(W_skip[(size_t)k * 384 + n]);
    } else if (idx < 147456) {
        int r = idx - 73728;
        int n = r / 192, k = r - n * 192;
        Wt[idx] = __float2bfloat16(W_xs[(size_t)k * 384 + n]);
    } else if (idx < 208896) {
        int r = idx - 147456;
        int n = r / 192, k = r - n * 192;
        Wt[idx] = __float2bfloat16(n < 262 ? W_bcdt[(size_t)k * 262 + n] : 0.f);
    } else if (idx < 282624) {
        int r = idx - 208896;
        int n = r / 384, k = r - n * 384;
        Wt[idx] = __float2bfloat16(W_out[(size_t)k * 192 + n] * norm_w[k]);
    }
}

// ---------------- MFMA GEMM body: MODE 0 plain, 1 silu, 2 dual ----------------
template<int MODE, typename AT, typename OutT>
DEV void mgemm_body(const AT* __restrict__ A0, const AT* __restrict__ A1,
                    const __hip_bfloat16* __restrict__ Wt, OutT* __restrict__ C,
                    OutT* __restrict__ C2, int N, int Kd, int i0, int j0)
{
    int t = threadIdx.x;
    int w = t >> 6, lane = t & 63;
    int lr = lane & 15, kq = lane >> 4;
    const AT* arow[2];
    #pragma unroll
    for (int a = 0; a < 2; ++a) {
        int grow = i0 + w * 32 + a * 16 + lr;
        const AT* Ap = (grow < 8192) ? A0 : A1;
        arow[a] = Ap + (size_t)(grow & 8191) * Kd;
    }
    f32x4 acc[2][4] = {};
    for (int k0 = 0; k0 < Kd; k0 += 32) {
        int kb = k0 + kq * 8;
        bf16x8 af[2];
        #pragma unroll
        for (int a = 0; a < 2; ++a) {
            if constexpr (sizeof(AT) == 4)
                af[a] = pack8(*(const float4*)(arow[a] + kb), *(const float4*)(arow[a] + kb + 4));
            else
                af[a] = *(const bf16x8*)(arow[a] + kb);
        }
        #pragma unroll
        for (int b = 0; b < 4; ++b) {
            int n = j0 + b * 16 + lr;
            bf16x8 bfr = *(const bf16x8*)(Wt + (size_t)n * Kd + kb);
            #pragma unroll
            for (int a = 0; a < 2; ++a)
                acc[a][b] = __builtin_amdgcn_mfma_f32_16x16x32_bf16(af[a], bfr, acc[a][b], 0, 0, 0);
        }
    }
    #pragma unroll
    for (int a = 0; a < 2; ++a)
        #pragma unroll
        for (int b = 0; b < 4; ++b)
            #pragma unroll
            for (int r = 0; r < 4; ++r) {
                int row = i0 + w * 32 + a * 16 + kq * 4 + r;
                int col = j0 + b * 16 + lr;
                float v = acc[a][b][r];
                if constexpr (MODE == 0) {
                    if (col < N) storeT(v, &C[(size_t)row * N + col]);
                } else if constexpr (MODE == 1) {
                    if (col < N) storeT(silu_f(v), &C[(size_t)row * N + col]);
                } else {
                    if (col < 384) storeT(silu_f(v), &C[(size_t)row * 384 + col]);
                    else           storeT(v, &C2[(size_t)row * 384 + col - 384]);
                }
            }
}

// ---------------- MERGED input GEMMs: skip+xs dual (1536) | bcdt (640) ----------------
__global__ __launch_bounds__(256) void mgemm_in_k(
    const float* __restrict__ u1, const float* __restrict__ u2,
    const float* __restrict__ u21, const float* __restrict__ u12,
    const __hip_bfloat16* __restrict__ Wt_skip, const __hip_bfloat16* __restrict__ Wt_bcdt,
    __hip_bfloat16* __restrict__ z_silu, __hip_bfloat16* __restrict__ pre_xs,
    __hip_bfloat16* __restrict__ pre_bc)
{
    int bid = blockIdx.x;
    if (bid < 1536) {
        mgemm_body<2, float, __hip_bfloat16>(u1, u2, Wt_skip, z_silu, pre_xs,
                                             768, 192, (bid / 12) * 128, (bid % 12) * 64);
    } else {
        int b = bid - 1536;               // 640 blocks: (5, 128)
        mgemm_body<0, float, __hip_bfloat16>(u21, u12, Wt_bcdt, pre_bc, nullptr,
                                             CBC, 192, (b / 5) * 128, (b % 5) * 64);
    }
}

// ---------------- conv16<STRIDE>: halo-load + dwconv 16 channels into smem-ls ----------------
// smem layout: raw(h,w,c) = smem[(h*18+w)*17+c] (read phase); then ls(h,w,c) = smem[(h*17+w)*17+c]
template<int STRIDE>
DEV void conv16(const __hip_bfloat16* __restrict__ pre, const float* __restrict__ cw,
                const float* __restrict__ cbia, int g, int h0, int w0, int chb,
                float* smem, float (*wsm)[9], float* bsm, int t)
{
    if (t < 144) wsm[t / 9][t % 9] = cw[(chb + t / 9) * 9 + t % 9];
    if (t < 16)  bsm[t] = cbia[chb + t];
    for (int i = t; i < 18 * 18 * 8; i += 256) {
        int cp = i & 7;
        int hw = i >> 3;
        int ww2 = hw % 18, hh = hw / 18;
        int gh = h0 - 1 + hh, gw = w0 - 1 + ww2;
        float v0 = 0.f, v1 = 0.f;
        if ((unsigned)gh < 64u && (unsigned)gw < 64u) {
            bf16x2 pv = *(const bf16x2*)(pre + ((size_t)g * LL + gh * 64 + gw) * STRIDE + chb + cp * 2);
            v0 = bf2f(pv[0]); v1 = bf2f(pv[1]);
        }
        smem[(hh * 18 + ww2) * 17 + cp * 2]     = v0;
        smem[(hh * 18 + ww2) * 17 + cp * 2 + 1] = v1;
    }
    __syncthreads();
    int h = t >> 4, w2 = t & 15;
    float out[16];
    #pragma unroll
    for (int ch = 0; ch < 16; ++ch) {
        float acc = bsm[ch];
        #pragma unroll
        for (int dy = 0; dy < 3; ++dy)
            #pragma unroll
            for (int dx = 0; dx < 3; ++dx)
                acc += smem[((h + dy) * 18 + (w2 + dx)) * 17 + ch] * wsm[ch][dy * 3 + dx];
        out[ch] = silu_f(acc);
    }
    __syncthreads();
    #pragma unroll
    for (int ch = 0; ch < 16; ++ch)
        smem[(h * 17 + w2) * 17 + ch] = out[ch];
    __syncthreads();
}

// ---------------- FUSED prep: bt (2048) | cs/bs (2048) | dtscan (1536) | xtc (1536) ----------------
__global__ __launch_bounds__(256) void prep_k(
    const __hip_bfloat16* __restrict__ pre_bc, const float* __restrict__ cbw,
    const float* __restrict__ cbb, const __hip_bfloat16* __restrict__ pre_xs,
    const float* __restrict__ cxw, const float* __restrict__ cxb,
    const float* __restrict__ dt_bias, const float* __restrict__ A_logs,
    __hip_bfloat16* __restrict__ Bt, __hip_bfloat16* __restrict__ Cs,
    __hip_bfloat16* __restrict__ Bs, __hip_bfloat16* __restrict__ XtG,
    float* __restrict__ dt_arr, float* __restrict__ ac_arr,
    float* __restrict__ cdecay)
{
    __shared__ float smem[18 * 18 * 17];  // raw halo, later aliased as ls
    __shared__ float wsm[16][9];
    __shared__ float bsm[16];
    __shared__ float wsum[4];
    int bid = blockIdx.x;
    int t = threadIdx.x;
    if (bid < 2048) {
        // ---- Bt[g][n 512][s 4096], all 4 dirs; conv fused ----
        int nt = bid & 31;
        int rest = bid >> 5;
        int wt = rest & 3, ht2 = (rest >> 2) & 3, g = rest >> 4;
        int h0 = ht2 * 16, w0 = wt * 16;
        int kd = nt >> 3, ch0 = (nt & 7) * 16;       // B channels 0..127
        conv16<262>(pre_bc, cbw, cbb, g, h0, w0, ch0, smem, wsm, bsm, t);
        int pc = t >> 4, q = t & 15;
        int n = nt * 16 + pc;
        __hip_bfloat16* rowp = Bt + ((size_t)g * 512 + n) * 4096;
        float v[16];
        if (kd == 0) {
            #pragma unroll
            for (int e = 0; e < 16; ++e) v[e] = smem[(q * 17 + e) * 17 + pc];
            store16(rowp + (h0 + q) * 64 + w0, v);
        } else if (kd == 1) {
            #pragma unroll
            for (int e = 0; e < 16; ++e) v[e] = smem[(e * 17 + q) * 17 + pc];
            store16(rowp + (w0 + q) * 64 + h0, v);
        } else if (kd == 2) {
            #pragma unroll
            for (int e = 0; e < 16; ++e) v[e] = smem[(q * 17 + 15 - e) * 17 + pc];
            store16(rowp + 4095 - (h0 + q) * 64 - w0 - 15, v);
        } else {
            #pragma unroll
            for (int e = 0; e < 16; ++e) v[e] = smem[((15 - e) * 17 + q) * 17 + pc];
            store16(rowp + 4095 - (w0 + q) * 64 - h0 - 15, v);
        }
    } else if (bid < 4096) {
        // ---- Cs / Bs scan tensors [g][s][256] (kd0/kd1; kd2/3 read row 4095-s); conv fused ----
        int b2 = bid - 2048;
        int ct = b2 & 31;
        int rest = b2 >> 5;
        int wt = rest & 3, ht2 = (rest >> 2) & 3, g = rest >> 4;
        int h0 = ht2 * 16, w0 = wt * 16;
        bool isB = ct >= 16;
        int ctl = ct & 15;
        int kd = ctl >> 3, ch0 = (ctl & 7) * 16;
        int chb = (isB ? 0 : 128) + ch0;
        conv16<262>(pre_bc, cbw, cbb, g, h0, w0, chb, smem, wsm, bsm, t);
        __hip_bfloat16* dst = isB ? Bs : Cs;
        int h = t >> 4, w2 = t & 15;
        int s = (kd == 0) ? (h0 + h) * 64 + (w0 + w2) : (w0 + w2) * 64 + (h0 + h);
        float v[16];
        #pragma unroll
        for (int e = 0; e < 16; ++e) v[e] = smem[(h * 17 + w2) * 17 + e];
        store16(dst + ((size_t)g * 4096 + s) * 256 + kd * 128 + ch0, v);
    } else if (bid < 5632) {
        // ---- dt: 9-tap conv inline + softplus + per-chunk cumsum (shuffle scan) ----
        int b3 = bid - 4096;              // ht + 24*(c + 16*g), 1536
        int ht = b3 % 24;
        int gc = b3 / 24;
        int c = gc & 15, g = gc >> 4;
        int k = ht / 6, h = ht % 6;
        int s = c * 256 + t;
        int l = map_l(s, k);
        int ch = 256 + h;
        float acc = cbb[ch];
        int hh0 = l >> 6, ww0 = l & 63;
        #pragma unroll
        for (int dy = 0; dy < 3; ++dy) {
            int gh = hh0 + dy - 1;
            if ((unsigned)gh >= 64u) continue;
            #pragma unroll
            for (int dx = 0; dx < 3; ++dx) {
                int gw = ww0 + dx - 1;
                if ((unsigned)gw >= 64u) continue;
                acc += __bfloat162float(pre_bc[((size_t)g * LL + gh * 64 + gw) * 262 + ch]) *
                       cbw[ch * 9 + dy * 3 + dx];
            }
        }
        float raw = silu_f(acc) + dt_bias[ht];
        float dtv = raw > 20.f ? raw : log1pf(__expf(raw));
        float dA = dtv * (-__expf(A_logs[ht]));
        float v = dA;
        #pragma unroll
        for (int off = 1; off < 64; off <<= 1) {
            float u = __shfl_up(v, off);
            if ((t & 63) >= off) v += u;
        }
        if ((t & 63) == 63) wsum[t >> 6] = v;
        __syncthreads();
        float add = 0.f;
        #pragma unroll
        for (int w2 = 0; w2 < 3; ++w2)
            if (w2 < (t >> 6)) add += wsum[w2];
        float cum = v + add;
        size_t base = ((size_t)g * 24 + ht) * LL + s;
        dt_arr[base] = dtv;
        ac_arr[base] = cum;
        if (t == 255) cdecay[(g * 24 + ht) * 16 + c] = __expf(cum);
    } else {
        // ---- xtc: dwconv(x) + transpose-store to XtG (2 scan dirs); conv fused ----
        int b4 = bid - 5632;              // 24 pct x 4 wt x 4 ht x 4 g = 1536
        int pct = b4 % 24;
        int rest = b4 / 24;
        int wt = rest & 3, ht2 = (rest >> 2) & 3, g = rest >> 4;
        int h0 = ht2 * 16, w0 = wt * 16, pc0 = pct * 16;
        conv16<384>(pre_xs, cxw, cxb, g, h0, w0, pc0, smem, wsm, bsm, t);
        int pc = t >> 4, q = t & 15;
        float v[16];
        size_t rowbase;
        #pragma unroll
        for (int e = 0; e < 16; ++e) v[e] = smem[(q * 17 + e) * 17 + pc];
        rowbase = ((size_t)(g * 2 + 0) * 384 + pc0 + pc) * 4096;
        store16(XtG + rowbase + (h0 + q) * 64 + w0, v);
        #pragma unroll
        for (int e = 0; e < 16; ++e) v[e] = smem[(e * 17 + q) * 17 + pc];
        rowbase = ((size_t)(g * 2 + 1) * 384 + pc0 + pc) * 4096;
        store16(XtG + rowbase + (w0 + q) * 64 + h0, v);
    }
}

// ---------------- MERGED cb (256) + states (3072): both depend only on prep ----------------
__global__ __launch_bounds__(256) void cbst_k(
    const __hip_bfloat16* __restrict__ Cs, const __hip_bfloat16* __restrict__ Bs,
    __hip_bfloat16* __restrict__ CBm,
    const __hip_bfloat16* __restrict__ XtG, const __hip_bfloat16* __restrict__ Bt,
    const float* __restrict__ dt_arr, const float* __restrict__ ac_arr,
    __hip_bfloat16* __restrict__ states)
{
    __shared__ float wsh[256];
    __shared__ short xw[64][264];         // weighted x, +8 pad -> 2-way bank alias (free)
    int bid = blockIdx.x;
    int t = threadIdx.x;
    int w = t >> 6, lane = t & 63;
    int lr = lane & 15, kq = lane >> 4;
    if (bid < 256) {
        // ---- CB[gc][i][j] = sum_n C[i,n]*B[j,n] ----
        int jq = bid & 3;
        int gc = bid >> 2;
        int c = gc & 15, g = gc >> 4;
        const __hip_bfloat16* cg = Cs + (size_t)g * 4096 * 256;
        const __hip_bfloat16* bsg = Bs + (size_t)g * 4096 * 256;
        f32x4 acc[4][4] = {};
        for (int ks = 0; ks < 16; ++ks) {
            int n0 = ks * 32 + kq * 8;
            int kd = n0 >> 7, nn = n0 & 127;
            int col = ((kd & 1) << 7) + nn;
            bf16x8 bfr[4];
            #pragma unroll
            for (int jt = 0; jt < 4; ++jt) {
                int j = jq * 64 + jt * 16 + lr;
                int s = c * 256 + j;
                int row = (kd < 2) ? s : 4095 - s;
                bfr[jt] = *(const bf16x8*)(bsg + (size_t)row * 256 + col);
            }
            #pragma unroll
            for (int iq = 0; iq < 4; ++iq) {
                int i = (w * 4 + iq) * 16 + lr;
                int s = c * 256 + i;
                int row = (kd < 2) ? s : 4095 - s;
                bf16x8 af = *(const bf16x8*)(cg + (size_t)row * 256 + col);
                #pragma unroll
                for (int jt = 0; jt < 4; ++jt)
                    acc[iq][jt] = __builtin_amdgcn_mfma_f32_16x16x32_bf16(af, bfr[jt], acc[iq][jt], 0, 0, 0);
            }
        }
        __hip_bfloat16* ob = CBm + (size_t)gc * 65536;
        #pragma unroll
        for (int iq = 0; iq < 4; ++iq)
            #pragma unroll
            for (int jt = 0; jt < 4; ++jt)
                #pragma unroll
                for (int r = 0; r < 4; ++r) {
                    int i = (w * 4 + iq) * 16 + kq * 4 + r;
                    int j = jq * 64 + jt * 16 + lr;
                    ob[(size_t)i * 256 + j] = __float2bfloat16(acc[iq][jt][r]);
                }
        return;
    }
    // ---- states, n-split: S[p, n-half] = sum_j w_j x[j,p] B[j,n] ----
    int sb = bid - 256;
    int task = (sb & 7) * 384 + (sb >> 3);  // XCD swizzle (perf only)
    int ht = task % 24;
    int rest = task / 24;                 // nh + 2*gc
    int nh = rest & 1;
    int gc = rest >> 1;
    int c = gc & 15, g = gc >> 4;
    int kd = ht / 6;
    bool rev = kd >= 2;
    int c0 = (ht % 6) * 64;
    int n0 = nh * 256;
    const float* dtp = dt_arr + ((size_t)g * 24 + ht) * LL + c * 256;
    const float* acp = ac_arr + ((size_t)g * 24 + ht) * LL + c * 256;
    float ac_last = acp[255];
    wsh[t] = __expf(ac_last - acp[t]) * dtp[t];
    __syncthreads();
    const __hip_bfloat16* xg = XtG + ((size_t)(g * 2 + (kd & 1)) * 384 + c0) * 4096;
    #pragma unroll
    for (int r8 = 0; r8 < 8; ++r8) {
        int id = t + 256 * r8;            // 0..2047
        int p = id >> 5;
        int jc = (id & 31) * 8;
        bf16x8 xv;
        if (!rev) {
            xv = *(const bf16x8*)(xg + (size_t)p * 4096 + c * 256 + jc);
        } else {
            bf16x8 tmp = load8u(xg + (size_t)p * 4096 + 4088 - c * 256 - jc);
            #pragma unroll
            for (int e = 0; e < 8; ++e) xv[e] = tmp[7 - e];
        }
        bf16x8 o;
        #pragma unroll
        for (int e = 0; e < 8; ++e) o[e] = f2bf(bf2f(xv[e]) * wsh[jc + e]);
        *(bf16x8*)&xw[p][jc] = o;
    }
    __syncthreads();
    const __hip_bfloat16* btg = Bt + ((size_t)g * 512 + n0) * 4096;
    f32x4 acc[4][4] = {};                 // [pt][nt], 64p x 256n (this half)
    for (int ks = 0; ks < 8; ++ks) {
        int j0 = ks * 32 + kq * 8;
        bf16x8 af[4];
        #pragma unroll
        for (int pt = 0; pt < 4; ++pt)
            af[pt] = *(const bf16x8*)&xw[pt * 16 + lr][j0];
        #pragma unroll
        for (int nt = 0; nt < 4; ++nt) {
            int nl = (w * 4 + nt) * 16 + lr;
            bf16x8 bv = *(const bf16x8*)(btg + (size_t)nl * 4096 + c * 256 + j0);
            #pragma unroll
            for (int pt = 0; pt < 4; ++pt)
                acc[pt][nt] = __builtin_amdgcn_mfma_f32_16x16x32_bf16(af[pt], bv, acc[pt][nt], 0, 0, 0);
        }
    }
    __hip_bfloat16* ob = states + ((size_t)gc * 24 + ht) * 32768 + n0;
    #pragma unroll
    for (int pt = 0; pt < 4; ++pt)
        #pragma unroll
        for (int nt = 0; nt < 4; ++nt)
            #pragma unroll
            for (int r = 0; r < 4; ++r) {
                int p = pt * 16 + kq * 4 + r;
                int nl = (w * 4 + nt) * 16 + lr;
                ob[(size_t)p * 512 + nl] = __float2bfloat16(acc[pt][nt][r]);
            }
}

// ---------------- inter-chunk scan, in place (vectorized bf16x8) ----------------
__global__ void scan_k(__hip_bfloat16* __restrict__ states, const float* __restrict__ cdecay)
{
    int idx = blockIdx.x * 256 + threadIdx.x;   // GG*24*64*512/8 = 393,216
    int g = idx / 98304;
    int r = idx - g * 98304;
    int ht = r >> 12;
    int pn8 = (r & 4095) * 8;
    const float* cd = cdecay + (g * 24 + ht) * 16;
    __hip_bfloat16* base = states + ((size_t)g * 384 + ht) * 32768 + pn8;
    float S[8] = {};
    #pragma unroll
    for (int c2 = 0; c2 < 16; ++c2) {
        bf16x8* p = (bf16x8*)(base + (size_t)c2 * 786432);
        bf16x8 tmp = *p;
        bf16x8 o;
        float dec = cd[c2];
        #pragma unroll
        for (int e = 0; e < 8; ++e) {
            o[e] = f2bf(S[e]);
            S[e] = S[e] * dec + bf2f(tmp[e]);
        }
        *p = o;
    }
}

// ---------------- MFMA y (round-13 proven shape): x LDS-staged upfront ----------------
__global__ __launch_bounds__(256) void yk(
    const __hip_bfloat16* __restrict__ XtG, const __hip_bfloat16* __restrict__ Cs,
    const __hip_bfloat16* __restrict__ CBm, const __hip_bfloat16* __restrict__ prev,
    const float* __restrict__ dt_arr, const float* __restrict__ ac_arr,
    const float* __restrict__ Ds, __hip_bfloat16* __restrict__ y4)
{
    __shared__ float acs[256], dts[256], ejdt[256];
    __shared__ short xl[64][264];         // x tile (scan order, rev folded), +8 pad
    int task = (blockIdx.x & 7) * 192 + (blockIdx.x >> 3);  // XCD swizzle (perf only)
    int ht = task % 24;
    int gc = task / 24;
    int c = gc & 15, g = gc >> 4;
    int kd = ht / 6;
    bool rev = kd >= 2;
    int c0 = (ht % 6) * 64;
    int t = threadIdx.x;
    int w = t >> 6, lane = t & 63;
    int lr = lane & 15, kq = lane >> 4;
    size_t abase = ((size_t)g * 24 + ht) * LL + c * 256;
    float ac_own = ac_arr[abase + t];
    float dt_own = dt_arr[abase + t];
    acs[t] = ac_own;
    dts[t] = dt_own;
    float acb0 = __shfl(ac_own, (t & 63) & ~31);
    ejdt[t] = __expf(acb0 - ac_own) * dt_own;
    const __hip_bfloat16* xg = XtG + ((size_t)(g * 2 + (kd & 1)) * 384 + c0) * 4096;
    #pragma unroll
    for (int r8 = 0; r8 < 8; ++r8) {
        int id = t + 256 * r8;
        int p = id >> 5;
        int jc = (id & 31) * 8;
        bf16x8 xv;
        if (!rev) {
            xv = *(const bf16x8*)(xg + (size_t)p * 4096 + c * 256 + jc);
        } else {
            bf16x8 tmp = load8u(xg + (size_t)p * 4096 + 4088 - c * 256 - jc);
            #pragma unroll
            for (int e = 0; e < 8; ++e) xv[e] = tmp[7 - e];
        }
        *(bf16x8*)&xl[p][jc] = xv;
    }
    __syncthreads();
    const __hip_bfloat16* cbb = CBm + (size_t)gc * 65536;
    const __hip_bfloat16* cg = Cs + (size_t)g * 4096 * 256;
    f32x4 acc[4][4] = {};
    // ---- term2 FIRST (unscaled): C @ prev^T, ping-pong double-buffered loads ----
    const __hip_bfloat16* pv = prev + ((size_t)gc * 24 + ht) * 32768;
    auto ld2 = [&](int ns, bf16x8* afq, bf16x8* pb) {
        int n0 = ns * 32 + kq * 8;
        int kd2 = n0 >> 7, nn = n0 & 127;
        int col = ((kd2 & 1) << 7) + nn;
        #pragma unroll
        for (int q = 0; q < 4; ++q) {
            int i = (w + 4 * q) * 16 + lr;
            int s = c * 256 + i;
            int row = (kd2 < 2) ? s : 4095 - s;
            afq[q] = *(const bf16x8*)(cg + (size_t)row * 256 + col);
        }
        #pragma unroll
        for (int pt = 0; pt < 4; ++pt)
            pb[pt] = *(const bf16x8*)(pv + (size_t)(pt * 16 + lr) * 512 + n0);
    };
    auto fma2 = [&](bf16x8* afq, bf16x8* pb) {
        #pragma unroll
        for (int q = 0; q < 4; ++q)
            #pragma unroll
            for (int pt = 0; pt < 4; ++pt)
                acc[q][pt] = __builtin_amdgcn_mfma_f32_16x16x32_bf16(afq[q], pb[pt], acc[q][pt], 0, 0, 0);
    };
    {
        bf16x8 afA[4], pbA[4], afB[4], pbB[4];
        ld2(0, afA, pbA);
        #pragma unroll
        for (int ns = 0; ns < 16; ns += 2) {
            if (ns + 1 < 16) ld2(ns + 1, afB, pbB);
            fma2(afA, pbA);
            if (ns + 2 < 16) ld2(ns + 2, afA, pbA);
            fma2(afB, pbB);
        }
    }
    // ---- scale term2 by exp(ac_i) in place ----
    #pragma unroll
    for (int q = 0; q < 4; ++q)
        #pragma unroll
        for (int r = 0; r < 4; ++r) {
            float er = __expf(acs[(w + 4 * q) * 16 + kq * 4 + r]);
            #pragma unroll
            for (int pt = 0; pt < 4; ++pt) acc[q][pt][r] *= er;
        }
    // ---- term1: causal M @ x; M = CB * exp(ac_i-ac_b) * ejdt; x from LDS ----
    float aci_q[4];
    #pragma unroll
    for (int q = 0; q < 4; ++q) aci_q[q] = acs[(w + 4 * q) * 16 + lr];
    for (int ks = 0; ks < 8; ++ks) {
        int j0 = ks * 32 + kq * 8;
        bf16x8 xb[4];
        #pragma unroll
        for (int pt = 0; pt < 4; ++pt)
            xb[pt] = *(const bf16x8*)&xl[pt * 16 + lr][j0];
        float acb = acs[ks * 32];
        float ej[8];
        #pragma unroll
        for (int e = 0; e < 8; ++e) ej[e] = ejdt[j0 + e];
        #pragma unroll
        for (int q = 0; q < 4; ++q) {
            int rt = w + 4 * q;
            if (rt < 2 * ks) continue;               // whole j-block above diagonal
            int i = rt * 16 + lr;
            float r2 = __expf(aci_q[q] - acb);
            bf16x8 cb8 = *(const bf16x8*)(cbb + (size_t)i * 256 + j0);
            bf16x8 af;
            if (rt >= 2 * ks + 2) {                  // full tile: no mask needed
                #pragma unroll
                for (int e = 0; e < 8; ++e)
                    af[e] = f2bf(r2 * ej[e] * bf2f(cb8[e]));
            } else {                                 // diagonal tile
                #pragma unroll
                for (int e = 0; e < 8; ++e) {
                    float coef = r2 * ej[e] * bf2f(cb8[e]);
                    af[e] = (j0 + e <= i) ? f2bf(coef) : (short)0;
                }
            }
            #pragma unroll
            for (int pt = 0; pt < 4; ++pt)
                acc[q][pt] = __builtin_amdgcn_mfma_f32_16x16x32_bf16(af, xb[pt], acc[q][pt], 0, 0, 0);
        }
    }
    // ---- epilogue: + Ds*x (from LDS), coalesced bf16 store to y4 (scan order) ----
    float Dsv = Ds[ht];
    __hip_bfloat16* yb = y4 + (((size_t)(g * 4 + kd) * 4096 + c * 256) * 384) + c0;
    #pragma unroll
    for (int q = 0; q < 4; ++q) {
        int rt = w + 4 * q;
        #pragma unroll
        for (int pt = 0; pt < 4; ++pt) {
            int p = pt * 16 + lr;
            int ibase = rt * 16 + kq * 4;
            bf16x4v x4 = *(const bf16x4v*)&xl[p][ibase];
            #pragma unroll
            for (int r = 0; r < 4; ++r) {
                int i = ibase + r;
                float xv = bf2f(x4[r]);
                yb[(size_t)i * 384 + p] = __float2bfloat16(acc[q][pt][r] + Dsv * xv);
            }
        }
    }
}

// ---------------- FUSED gate + output GEMM: 512 blocks x 32 rows (occupancy fix) ----------------
// phase1: gate 32 rows (8 lanes/row, 48 cols each, f32 in regs -> bit-identical rounding),
//         bf16 gn tile to LDS. phase2: 32x192 MFMA GEMM (K=384) from LDS A, Wt_out B.
__global__ __launch_bounds__(256) void gateout_k(
    const __hip_bfloat16* __restrict__ y4, const __hip_bfloat16* __restrict__ z_silu,
    const __hip_bfloat16* __restrict__ Wt_out, float* __restrict__ out)
{
    __shared__ short gnl[32][392];        // stride 784B: 196 dw, %32=4 -> 2 lanes/bank (free)
    int b = blockIdx.x;
    int t = threadIdx.x;
    int row0 = b * 32;
    // ---- phase 1: gate ----
    {
        int rloc = t >> 3, part = t & 7;
        int row = row0 + rloc;
        int g = row >> 12, l = row & 4095;
        int Tl = ((l & 63) << 6) | (l >> 6);
        const __hip_bfloat16* p0 = y4 + ((size_t)(g * 4 + 0) * 4096 + l) * 384;
        const __hip_bfloat16* p1 = y4 + ((size_t)(g * 4 + 1) * 4096 + Tl) * 384;
        const __hip_bfloat16* p2 = y4 + ((size_t)(g * 4 + 2) * 4096 + 4095 - l) * 384;
        const __hip_bfloat16* p3 = y4 + ((size_t)(g * 4 + 3) * 4096 + 4095 - Tl) * 384;
        const __hip_bfloat16* zp = z_silu + ((size_t)g * LL + l) * 384;
        int cb = part * 48;
        float vf[48];
        float ssq = 0.f;
        #pragma unroll
        for (int cg = 0; cg < 6; ++cg) {
            int cc = cb + cg * 8;
            bf16x8 a0 = *(const bf16x8*)(p0 + cc);
            bf16x8 a1 = *(const bf16x8*)(p1 + cc);
            bf16x8 a2 = *(const bf16x8*)(p2 + cc);
            bf16x8 a3 = *(const bf16x8*)(p3 + cc);
            bf16x8 zv = *(const bf16x8*)(zp + cc);
            #pragma unroll
            for (int e = 0; e < 8; ++e) {
                float yf = bf2f(a0[e]) + bf2f(a1[e]) + bf2f(a2[e]) + bf2f(a3[e]);
                float v = yf * bf2f(zv[e]);
                vf[cg * 8 + e] = v;
                ssq += v * v;
            }
        }
        ssq += __shfl_xor(ssq, 1);
        ssq += __shfl_xor(ssq, 2);
        ssq += __shfl_xor(ssq, 4);
        float rs = rsqrtf(ssq * (1.f / 384.f) + 1e-5f);
        #pragma unroll
        for (int cg = 0; cg < 6; ++cg) {
            bf16x8 o;
            #pragma unroll
            for (int e = 0; e < 8; ++e) o[e] = f2bf(vf[cg * 8 + e] * rs);
            *(bf16x8*)&gnl[rloc][cb + cg * 8] = o;
        }
    }
    __syncthreads();
    // ---- phase 2: 32x192 GEMM, K=384; wave w: rowTile (w>>1), colHalf (w&1) ----
    int w = t >> 6, lane = t & 63;
    int lr = lane & 15, kq = lane >> 4;
    int rowTile = w >> 1, colHalf = w & 1;
    f32x4 acc[6] = {};
    for (int k0 = 0; k0 < 384; k0 += 32) {
        int kb = k0 + kq * 8;
        bf16x8 af = *(const bf16x8*)&gnl[rowTile * 16 + lr][kb];
        #pragma unroll
        for (int b2 = 0; b2 < 6; ++b2) {
            int n = colHalf * 96 + b2 * 16 + lr;
            bf16x8 bfr = *(const bf16x8*)(Wt_out + (size_t)n * 384 + kb);
            acc[b2] = __builtin_amdgcn_mfma_f32_16x16x32_bf16(af, bfr, acc[b2], 0, 0, 0);
        }
    }
    #pragma unroll
    for (int b2 = 0; b2 < 6; ++b2)
        #pragma unroll
        for (int r = 0; r < 4; ++r) {
            int row = row0 + rowTile * 16 + kq * 4 + r;
            int col = colHalf * 96 + b2 * 16 + lr;
            out[(size_t)row * 192 + col] = acc[b2][r];
        }
}

extern "C" void kernel_launch(void* const* d_in, const int* in_sizes, int n_in,
                              void* d_out, int out_size, void* d_ws, size_t ws_size,
                              hipStream_t stream)
{
    const float* u1      = (const float*)d_in[0];
    const float* u2      = (const float*)d_in[1];
    const float* u21     = (const float*)d_in[2];
    const float* u12     = (const float*)d_in[3];
    const float* W_skip  = (const float*)d_in[4];
    const float* W_xs    = (const float*)d_in[5];
    const float* W_bcdt  = (const float*)d_in[6];
    const float* cxw     = (const float*)d_in[7];
    const float* cxb     = (const float*)d_in[8];
    const float* cbw     = (const float*)d_in[9];
    const float* cbb     = (const float*)d_in[10];
    const float* dt_bias = (const float*)d_in[11];
    const float* A_logs  = (const float*)d_in[12];
    const float* Ds      = (const float*)d_in[13];
    const float* norm_w  = (const float*)d_in[14];
    const float* W_out   = (const float*)d_in[15];
    float* out = (float*)d_out;

    char* w = (char*)d_ws;
    size_t o_y4  = 0;                         // 50,331,648 bf16 y4
    size_t o_st  = o_y4 + 50331648;           // 100,663,296 bf16 states/prev (early: pre_bc@0, pre_xs@8.65M)
    size_t o_z   = o_st + 100663296;          // 12,582,912 bf16 z_silu
    size_t o_xtg = o_z  + 12582912;           // 25,165,824 bf16 XtG (2 dirs)
    size_t o_bt  = o_xtg + 25165824;          // 16,777,216 bf16 Bt
    size_t o_cs  = o_bt + 16777216;           //  8,388,608 bf16 C_scan
    size_t o_cbm = o_cs + 8388608;            //  8,388,608 bf16 CBm
    size_t o_dt  = o_cbm + 8388608;           //  1,572,864 f32 dt_arr
    size_t o_ac  = o_dt + 1572864;            //  1,572,864 f32 ac_arr
    size_t o_cd  = o_ac + 1572864;            //      8,192 f32 cdecay
    size_t o_wt  = o_cd + 8192;               //    589,824 bf16 Wt (skip|xs|bcdt|out)
    size_t o_bs  = o_wt + 589824;             //  8,388,608 bf16 B_scan
    size_t total = o_bs + 8388608;            // = 234,430,464 B (< proven 238.5 MB)
    if (total > ws_size) {
        sentinel_k<<<1, 1, 0, stream>>>(out); // absmax ~1e30 => workspace too small
        return;
    }
    __hip_bfloat16* y4     = (__hip_bfloat16*)(w + o_y4);
    __hip_bfloat16* states = (__hip_bfloat16*)(w + o_st);
    __hip_bfloat16* z_silu = (__hip_bfloat16*)(w + o_z);
    __hip_bfloat16* XtG    = (__hip_bfloat16*)(w + o_xtg);
    __hip_bfloat16* Bt     = (__hip_bfloat16*)(w + o_bt);
    __hip_bfloat16* Cs     = (__hip_bfloat16*)(w + o_cs);
    __hip_bfloat16* CBm    = (__hip_bfloat16*)(w + o_cbm);
    float*          dt_arr = (float*)(w + o_dt);
    float*          ac_arr = (float*)(w + o_ac);
    float*          cdecay = (float*)(w + o_cd);
    __hip_bfloat16* Wt     = (__hip_bfloat16*)(w + o_wt);
    __hip_bfloat16* Bs     = (__hip_bfloat16*)(w + o_bs);
    __hip_bfloat16* Wt_skip = Wt;                       // skip|xs contiguous (N=768)
    __hip_bfloat16* Wt_bcdt = Wt + 147456;
    __hip_bfloat16* Wt_out  = Wt + 208896;
    // transient aliases
    __hip_bfloat16* pre_bc = (__hip_bfloat16*)(w + o_st);           // dead after prep_k
    __hip_bfloat16* pre_xs = (__hip_bfloat16*)(w + o_st + 8650752); // dead after prep_k

    dim3 blk(256);
    // 0. fused weight transposes (norm_w folded into Wt_out)
    wt_all_k<<<dim3(1104), blk, 0, stream>>>(W_skip, W_xs, W_bcdt, W_out, norm_w, Wt);
    // 1. merged input GEMMs (MFMA): skip+xs dual-out | bcdt
    mgemm_in_k<<<dim3(2176), blk, 0, stream>>>(u1, u2, u21, u12, Wt_skip, Wt_bcdt,
                                               z_silu, pre_xs, pre_bc);
    // 2. fused prep: Bt | Cs/Bs | dtscan | xtc (one dispatch, conv inline)
    prep_k<<<dim3(7168), blk, 0, stream>>>(pre_bc, cbw, cbb, pre_xs, cxw, cxb,
                                           dt_bias, A_logs, Bt, Cs, Bs, XtG,
                                           dt_arr, ac_arr, cdecay);
    // 3. merged CB (MFMA) + per-chunk states (MFMA, XCD-swizzled, n-split)
    cbst_k<<<dim3(3328), blk, 0, stream>>>(Cs, Bs, CBm, XtG, Bt, dt_arr, ac_arr, states);
    // 4. inter-chunk scan (in place -> prev states, bf16x8-vectorized)
    scan_k<<<dim3(1536), blk, 0, stream>>>(states, cdecay);
    // 5. y (MFMA, XCD-swizzled, x LDS-staged, full-p) -> per-direction y4
    yk<<<dim3(1536), blk, 0, stream>>>(XtG, Cs, CBm, states, dt_arr, ac_arr, Ds, y4);
    // 6. fused gate + RMSNorm + output GEMM (512 blocks x 32 rows; norm_w in Wt_out)
    gateout_k<<<dim3(512), blk, 0, stream>>>(y4, z_silu, Wt_out, out);
}